// Round 1
// baseline (447.912 us; speedup 1.0000x reference)
//
#include <hip/hip_runtime.h>

// Problem constants (reference: B=4096, CELL=400, K=10, T=256, V=80)
#define BB   4096
#define CELL 400
#define KK   10
#define TT   256
#define VV   80
// 3K = 30 params per row; block = 320 threads (5 waves)

__global__ __launch_bounds__(320) void window_kernel(
    const float* __restrict__ x,         // [B, CELL]
    const float* __restrict__ kappa_old, // [B, K]
    const float* __restrict__ onehots,   // [B, T, V]
    const float* __restrict__ W,         // [3K, CELL]
    const float* __restrict__ bias,      // [3K]
    float* __restrict__ out)             // [B*V weight][B*K kappa] concatenated
{
    __shared__ float  x_lds[CELL];
    __shared__ float  p_lds[30];
    __shared__ float  alpha_lds[KK], beta_lds[KK], kappa_lds[KK];
    __shared__ float  phi_lds[TT];
    __shared__ float4 part_lds[320];

    const int b   = blockIdx.x;
    const int tid = threadIdx.x;

    // ---- Phase 1a: stage x row into LDS (100 float4 = 400 floats) ----
    if (tid < 100) {
        const float4* x4 = (const float4*)(x + (size_t)b * CELL);
        ((float4*)x_lds)[tid] = x4[tid];
    }
    __syncthreads();

    // ---- Phase 1b: params = x @ W^T + b  (30 outputs x 8 lanes x 50 elems) ----
    if (tid < 240) {
        const int j = tid >> 3;        // output index 0..29
        const int r = tid & 7;         // lane-in-group
        const float* wrow = W + j * CELL + r * 50;
        const float* xs   = x_lds + r * 50;
        float s = 0.f;
        #pragma unroll
        for (int i = 0; i < 50; ++i) s += xs[i] * wrow[i];
        s += __shfl_down(s, 4, 8);
        s += __shfl_down(s, 2, 8);
        s += __shfl_down(s, 1, 8);
        if (r == 0) p_lds[j] = s + bias[j];
    }
    __syncthreads();

    // ---- Phase 2: alpha/beta/kappa; write kappa output ----
    if (tid < KK) {
        float a  = __expf(p_lds[tid]);
        float be = __expf(p_lds[KK + tid]);
        float ka = kappa_old[(size_t)b * KK + tid] + __expf(p_lds[2 * KK + tid]);
        alpha_lds[tid] = a;
        beta_lds[tid]  = be;
        kappa_lds[tid] = ka;
        out[(size_t)BB * VV + (size_t)b * KK + tid] = ka;
    }
    __syncthreads();

    // ---- Phase 3: phi[t] = sum_k alpha_k * exp(-beta_k * (kappa_k - t)^2) ----
    if (tid < TT) {
        const float u = (float)tid;
        float s = 0.f;
        #pragma unroll
        for (int k = 0; k < KK; ++k) {
            float d = kappa_lds[k] - u;
            s += alpha_lds[k] * __expf(-beta_lds[k] * d * d);
        }
        phi_lds[tid] = s;
    }
    __syncthreads();

    // ---- Phase 4: weight[v] = sum_t phi[t] * onehots[b,t,v] ----
    // Row is 256*80 floats = 5120 float4. tid = g*20+vv; flat float4 index
    // tid + 320*it is fully contiguous per iteration (perfect coalescing).
    {
        const float4* oh4 = (const float4*)(onehots + (size_t)b * TT * VV);
        const int g = tid / 20;  // 0..15
        float4 acc = {0.f, 0.f, 0.f, 0.f};
        #pragma unroll
        for (int it = 0; it < 16; ++it) {
            const int t = g + 16 * it;
            const float ph = phi_lds[t];
            const float4 o = oh4[tid + 320 * it];
            acc.x += ph * o.x;
            acc.y += ph * o.y;
            acc.z += ph * o.z;
            acc.w += ph * o.w;
        }
        part_lds[tid] = acc;
    }
    __syncthreads();

    // ---- Phase 5: reduce 16 partials per v-float4, store weight ----
    if (tid < 20) {
        float4 s = {0.f, 0.f, 0.f, 0.f};
        #pragma unroll
        for (int g = 0; g < 16; ++g) {
            const float4 p = part_lds[g * 20 + tid];
            s.x += p.x; s.y += p.y; s.z += p.z; s.w += p.w;
        }
        float4* o4 = (float4*)(out + (size_t)b * VV);
        o4[tid] = s;
    }
}

extern "C" void kernel_launch(void* const* d_in, const int* in_sizes, int n_in,
                              void* d_out, int out_size, void* d_ws, size_t ws_size,
                              hipStream_t stream) {
    const float* x         = (const float*)d_in[0];
    const float* kappa_old = (const float*)d_in[1];
    const float* onehots   = (const float*)d_in[2];
    const float* W         = (const float*)d_in[3];
    const float* bias      = (const float*)d_in[4];
    // d_in[5] = text_len (=256), compile-time constant here
    float* out = (float*)d_out;

    window_kernel<<<BB, 320, 0, stream>>>(x, kappa_old, onehots, W, bias, out);
}